// Round 9
// baseline (397.188 us; speedup 1.0000x reference)
//
#include <hip/hip_runtime.h>
#include <cmath>

// Child-sum TreeLSTM over a perfect binary heap (parent[i]=(i-1)/2, N=1023),
// level-by-level fp16 MFMA GEMMs (fp32 accumulate).
//
// R8: counted-vmcnt software pipeline (guide T4). 4-buffer LDS ring (64 KB),
// global_load_lds staged 2 K-steps ahead; per-wave s_waitcnt vmcnt(8) + raw
// s_barrier instead of __syncthreads' vmcnt(0) drain (which stalled every
// K-step ~3000 cyc at L2/HBM latency -> MfmaUtil stuck at 25%).
// nsteps is always divisible by 4 (8 or 24), so the last compute buffer is
// buf3 and the epilogue LDS alias (bufs 0..2) is race-free without a drain.

typedef _Float16 f16;
typedef _Float16 f16x8 __attribute__((ext_vector_type(8)));
typedef float f32x4 __attribute__((ext_vector_type(4)));

#define Nn 1023
#define En 256
#define Hn 512
#define EST 36    // epilogue LDS stride in floats

__device__ __forceinline__ float frcp_(float x){ return __builtin_amdgcn_rcpf(x); }
__device__ __forceinline__ float sigm(float x){ return frcp_(1.f + __expf(-x)); }
__device__ __forceinline__ float ftanh(float x){
  x = fminf(15.f, fmaxf(-15.f, x));
  float e = __expf(2.f * x);
  return (e - 1.f) * frcp_(e + 1.f);
}

__device__ __forceinline__ void gload16(const void* g, void* l) {
  __builtin_amdgcn_global_load_lds(
      (const __attribute__((address_space(1))) void*)g,
      (__attribute__((address_space(3))) void*)l, 16, 0, 0);
}

__global__ __launch_bounds__(256)
void prep_w(const float* __restrict__ Wiou, const float* __restrict__ Wf,
            const float* __restrict__ biou, const float* __restrict__ bfv,
            f16* __restrict__ Btp, float* __restrict__ bcomb)
{
  int c = blockIdx.x;            // 0..2047 interleaved col: c = 4*n + gate
  int n = c >> 2, g = c & 3;
  for (int k = threadIdx.x; k < 768; k += 256) {
    float v = (g < 3) ? Wiou[(size_t)k*1536 + g*512 + n] : Wf[(size_t)k*512 + n];
    Btp[(size_t)c*768 + k] = (f16)v;
  }
  if (threadIdx.x == 0) bcomb[c] = (g < 3) ? biou[g*512 + n] : bfv[n];
}

__global__ __launch_bounds__(256)
void prep_emb(const float* __restrict__ emb, f16* __restrict__ embh)
{
  size_t i = (size_t)blockIdx.x*256 + threadIdx.x;   // 2000*256 total
  embh[i] = (f16)emb[i];
}

// mode: 0 = inner pair level, 1 = leaf (K=256, csum=0), 2 = root (64 rows -> d_out)
// Block: 256 thr = 4 waves (2 wm x 2 wn). Tile: 128 wcols x 128 rows, BK=32.
// Grid: (pairs, 16) -- pair fast dim => same-pair col-blocks share an XCD L2.
// LDS ring: buf b at smem + b*16384; W tile [128 rows][64B] at +0, C tile at
// +8192. Row r's 16B slot s holds global k-slot s ^ ((r>>1)&3) (XOR involution
// applied on the pre-swizzled global source and again on the ds_read).
__global__ __launch_bounds__(256)
void lstm_level(const int* __restrict__ ast,
                const f16* __restrict__ embh,
                const f16* __restrict__ Btp,
                const float* __restrict__ bcomb,
                const f16* __restrict__ hsum_in,
                const float* __restrict__ csum_in,
                f16* __restrict__ hsum_out,
                float* __restrict__ csum_out,
                float* __restrict__ out_root,
                int level_start, int k_total, int mode)
{
  __shared__ __align__(16) char smem[65536];
  __shared__ int s_tok[128];
  float* csLDS = (float*)smem;              // epilogue: [128][EST] (bufs 0-2 alias)
  float* hLDS  = (float*)(smem + 18432);    // epilogue: [64][EST]
  float* cLDS  = (float*)(smem + 27648);    // epilogue: [64][EST]

  const int t = threadIdx.x;
  const int pair = blockIdx.x;
  const int bm = blockIdx.y;            // n-block (32 n per block)
  const int R0 = pair * 128;
  const int w = t >> 6, wm = w >> 1, wn = w & 1;
  const int lane = t & 63, l15 = lane & 15, kg4 = lane >> 4;
  const int n0 = bm * 32;
  const bool leaf = (mode == 1);

  if (t < 128) {
    int node = (mode == 2) ? 0 : (pair*2 + (t >> 6));
    s_tok[t] = ast[(size_t)(t & 63)*Nn + level_start + node];
  }

  // coalesced csum prefetch for the epilogue (in flight across the K-loop)
  float4 cs_pre[4];
  if (!leaf) {
    int row = t >> 1;
    int rows_cs = (mode == 2) ? 64 : 128;
    if (row < rows_cs) {
      const float* src = csum_in + (size_t)(R0 + row)*Hn + n0 + (t & 1)*16;
#pragma unroll
      for (int j = 0; j < 4; ++j) cs_pre[j] = *(const float4*)(src + j*4);
    } else {
#pragma unroll
      for (int j = 0; j < 4; ++j) cs_pre[j] = make_float4(0.f,0.f,0.f,0.f);
    }
  }
  __syncthreads();   // s_tok visible

  // ---- per-thread staging state (loop-invariant) ----
  const int srow = lane >> 2, sslot = lane & 3;
  const int rb0 = w*32, rb1 = w*32 + 16;
  const int row0 = rb0 + srow, row1 = rb1 + srow;
  const int ss0 = sslot ^ ((row0 >> 1) & 3), ss1 = sslot ^ ((row1 >> 1) & 3);
  const size_t wo0 = (size_t)(bm*128 + row0)*768 + ss0*8;
  const size_t wo1 = (size_t)(bm*128 + row1)*768 + ss1*8;
  const size_t ce0 = (size_t)s_tok[row0]*En + ss0*8;
  const size_t ce1 = (size_t)s_tok[row1]*En + ss1*8;
  const int rg0 = (mode == 2) ? (row0 & 63) : (R0 + row0);
  const int rg1 = (mode == 2) ? (row1 & 63) : (R0 + row1);
  const ptrdiff_t ch0 = (ptrdiff_t)rg0*Hn + ss0*8 - En;
  const ptrdiff_t ch1 = (ptrdiff_t)rg1*Hn + ss1*8 - En;
  const int klim0 = En - ss0*8, klim1 = En - ss1*8;

#define STAGE(bufc, K0)                                                        \
  {                                                                            \
    gload16(Btp + wo0 + (K0), (bufc) + rb0*64);                                \
    gload16(((K0) < klim0 ? embh + ce0 + (K0) : hsum_in + ch0 + (K0)),         \
            (bufc) + 8192 + rb0*64);                                           \
    gload16(Btp + wo1 + (K0), (bufc) + rb1*64);                                \
    gload16(((K0) < klim1 ? embh + ce1 + (K0) : hsum_in + ch1 + (K0)),         \
            (bufc) + 8192 + rb1*64);                                           \
  }

  // ---- loop-invariant ds_read byte offsets ----
  int offW[4], offC[4];
#pragma unroll
  for (int mi = 0; mi < 4; ++mi) {
    int row = wm*64 + mi*16 + l15;
    offW[mi] = row*64 + (kg4 ^ ((row >> 1) & 3))*16;
  }
#pragma unroll
  for (int ni = 0; ni < 4; ++ni) {
    int row = (ni >> 1)*64 + wn*32 + (ni & 1)*16 + l15;
    offC[ni] = 8192 + row*64 + (kg4 ^ ((row >> 1) & 3))*16;
  }

  f32x4 acc[4][4];
#pragma unroll
  for (int i = 0; i < 4; ++i)
#pragma unroll
    for (int j = 0; j < 4; ++j) acc[i][j] = (f32x4){0.f,0.f,0.f,0.f};

  const int nsteps = k_total >> 5;   // 8 (leaf) or 24 -- always % 4 == 0

  STAGE(smem, 0);
  __builtin_amdgcn_sched_barrier(0);
  STAGE(smem + 16384, 32);
  __builtin_amdgcn_sched_barrier(0);

  for (int s = 0; s < nsteps; ++s) {
    if (s + 2 < nsteps) {
      char* nb = smem + ((s + 2) & 3)*16384;
      STAGE(nb, (s + 2) << 5);
      __builtin_amdgcn_sched_barrier(0);
      asm volatile("s_waitcnt vmcnt(8)" ::: "memory");   // buf s done; s+1,s+2 in flight
    } else if (s + 2 == nsteps) {
      asm volatile("s_waitcnt vmcnt(4)" ::: "memory");   // buf s done; s+1 in flight
    } else {
      asm volatile("s_waitcnt vmcnt(0)" ::: "memory");   // last buf
    }
    __builtin_amdgcn_s_barrier();
    __builtin_amdgcn_sched_barrier(0);

    const char* cur = smem + (s & 3)*16384;
    f16x8 aW[4], aC[4];
#pragma unroll
    for (int mi = 0; mi < 4; ++mi) aW[mi] = *(const f16x8*)(cur + offW[mi]);
#pragma unroll
    for (int ni = 0; ni < 4; ++ni) aC[ni] = *(const f16x8*)(cur + offC[ni]);
#pragma unroll
    for (int mi = 0; mi < 4; ++mi)
#pragma unroll
      for (int ni = 0; ni < 4; ++ni)
        acc[mi][ni] = __builtin_amdgcn_mfma_f32_16x16x32_f16(aW[mi], aC[ni], acc[mi][ni], 0, 0, 0);
  }
  // After the s = nsteps-1 barrier, every wave only reads buf3 (48-64K);
  // the epilogue alias region (0-36.8K) is free.

  // ================= epilogue =================
  // phase A: csum regs -> LDS (lane-local layout)
  if (!leaf) {
    int row = t >> 1;
    int rows_cs = (mode == 2) ? 64 : 128;
    if (row < rows_cs) {
      float* dst = csLDS + row*EST + (t & 1)*16;
#pragma unroll
      for (int j = 0; j < 4; ++j) *(float4*)(dst + j*4) = cs_pre[j];
    }
  }
  __syncthreads();

  float hres[4][2], cres[4][2];
#pragma unroll
  for (int mi = 0; mi < 4; ++mi) {
    int nl = wm*16 + mi*4 + kg4;
    float4 bc = *(const float4*)(bcomb + (size_t)(n0 + nl)*4);
#pragma unroll
    for (int pi = 0; pi < 2; ++pi) {
      int brow = wn*32 + pi*16 + l15;
      f32x4 a0 = acc[mi][pi];                // sibling 0
      float i0 = sigm(a0[0] + bc.x);
      float o0 = sigm(a0[1] + bc.y);
      float u0 = ftanh(a0[2] + bc.z);
      float f0 = sigm(a0[3] + bc.w);
      float cs0 = leaf ? 0.f : csLDS[brow*EST + nl];
      float c0 = i0*u0 + f0*cs0;
      float h0 = o0 * ftanh(c0);
      if (mode == 2) {
        hres[mi][pi] = h0; cres[mi][pi] = 0.f;
      } else {
        f32x4 a1 = acc[mi][2 + pi];          // sibling 1
        float i1 = sigm(a1[0] + bc.x);
        float o1 = sigm(a1[1] + bc.y);
        float u1 = ftanh(a1[2] + bc.z);
        float f1 = sigm(a1[3] + bc.w);
        float cs1 = leaf ? 0.f : csLDS[(64 + brow)*EST + nl];
        float c1 = i1*u1 + f1*cs1;
        float h1 = o1 * ftanh(c1);
        hres[mi][pi] = h0 + h1;
        cres[mi][pi] = c0 + c1;
      }
    }
  }
  __syncthreads();

  // phase B: results -> LDS in (brow, nl)
#pragma unroll
  for (int mi = 0; mi < 4; ++mi) {
    int nl = wm*16 + mi*4 + kg4;
#pragma unroll
    for (int pi = 0; pi < 2; ++pi) {
      int brow = wn*32 + pi*16 + l15;
      hLDS[brow*EST + nl] = hres[mi][pi];
      if (mode != 2) cLDS[brow*EST + nl] = cres[mi][pi];
    }
  }
  __syncthreads();

  // coalesced stores: thread t -> row r = t>>2, cols c0 = (t&3)*8
  {
    int r = t >> 2;
    int c0 = (t & 3) * 8;
    if (mode == 2) {
      float4 v0 = *(const float4*)(hLDS + r*EST + c0);
      float4 v1 = *(const float4*)(hLDS + r*EST + c0 + 4);
      float* dst = out_root + (size_t)r*Hn + n0 + c0;
      *(float4*)dst = v0;
      *(float4*)(dst + 4) = v1;
    } else {
      f16x8 hv;
#pragma unroll
      for (int i = 0; i < 8; ++i) hv[i] = (f16)hLDS[r*EST + c0 + i];
      size_t orow = (size_t)(pair*64 + r)*Hn + n0 + c0;
      *(f16x8*)(hsum_out + orow) = hv;
      float4 v0 = *(const float4*)(cLDS + r*EST + c0);
      float4 v1 = *(const float4*)(cLDS + r*EST + c0 + 4);
      *(float4*)(csum_out + orow) = v0;
      *(float4*)(csum_out + orow + 4) = v1;
    }
  }
}

extern "C" void kernel_launch(void* const* d_in, const int* in_sizes, int n_in,
                              void* d_out, int out_size, void* d_ws, size_t ws_size,
                              hipStream_t stream) {
  const int*   ast  = (const int*)d_in[0];
  // d_in[1] = parent (int64): unused, tree is the fixed heap (i-1)/2
  const float* emb  = (const float*)d_in[2];
  const float* Wiou = (const float*)d_in[3];
  const float* biou = (const float*)d_in[4];
  const float* Wf   = (const float*)d_in[5];
  const float* bfv  = (const float*)d_in[6];
  float* out = (float*)d_out;

  char* ws = (char*)d_ws;
  f16*   Btp   = (f16*)ws;    ws += (size_t)2048*768*2;
  float* bcomb = (float*)ws;  ws += (size_t)2048*4;
  f16*   embh  = (f16*)ws;    ws += (size_t)2000*256*2;
  f16*   hA    = (f16*)ws;    ws += (size_t)16384*512*2;
  float* cA    = (float*)ws;  ws += (size_t)16384*512*4;
  f16*   hB    = (f16*)ws;    ws += (size_t)8192*512*2;
  float* cB    = (float*)ws;  ws += (size_t)8192*512*4;

  prep_w  <<<2048, 256, 0, stream>>>(Wiou, Wf, biou, bfv, Btp, bcomb);
  prep_emb<<<2000, 256, 0, stream>>>(emb, embh);

  // leaf level l=9 (512 nodes, K=256) -> level-8 sums into set A
  lstm_level<<<dim3(256, 16), 256, 0, stream>>>(
      ast, embh, Btp, bcomb, nullptr, nullptr, hA, cA, nullptr, 511, En, 1);

  const f16* ih = hA; const float* ic = cA; int wsel = 1;
  for (int l = 8; l >= 1; --l) {
    f16*   oh = wsel ? hB : hA;
    float* oc = wsel ? cB : cA;
    lstm_level<<<dim3(1 << (l - 1), 16), 256, 0, stream>>>(
        ast, embh, Btp, bcomb, ih, ic, oh, oc, nullptr, (1 << l) - 1, En + Hn, 0);
    ih = oh; ic = oc; wsel ^= 1;
  }
  // root (64 rows): reads level-0 sums, writes h_root fp32 to d_out
  lstm_level<<<dim3(1, 16), 256, 0, stream>>>(
      ast, embh, Btp, bcomb, ih, ic, nullptr, nullptr, out, 0, En + Hn, 2);
}

// Round 10
// 380.131 us; speedup vs baseline: 1.0449x; 1.0449x over previous
//
#include <hip/hip_runtime.h>
#include <cmath>

// Child-sum TreeLSTM over a perfect binary heap (parent[i]=(i-1)/2, N=1023),
// level-by-level fp16 MFMA GEMMs (fp32 accumulate).
//
// R10: pipeline depth routed by level size.
//  DEEP=0 (big levels: leaf, l8, l7; >=1024 blocks): 2-buffer LDS (37 KB),
//    __syncthreads-per-step -- 4 blocks/CU, TLP hides latency (R7: 85 us leaf).
//  DEEP=1 (small levels: l6..l1, root; <=512 blocks): 4-buffer ring (64 KB),
//    counted s_waitcnt vmcnt(8)+s_barrier, stage-ahead 2 -- ILP hides latency
//    where the grid can't fill the machine (R8 structure).
// R9 lesson: DEEP=1 on big levels loses 2x residency for no net gain.

typedef _Float16 f16;
typedef _Float16 f16x8 __attribute__((ext_vector_type(8)));
typedef float f32x4 __attribute__((ext_vector_type(4)));

#define Nn 1023
#define En 256
#define Hn 512
#define EST 36    // epilogue LDS stride in floats

__device__ __forceinline__ float frcp_(float x){ return __builtin_amdgcn_rcpf(x); }
__device__ __forceinline__ float sigm(float x){ return frcp_(1.f + __expf(-x)); }
__device__ __forceinline__ float ftanh(float x){
  x = fminf(15.f, fmaxf(-15.f, x));
  float e = __expf(2.f * x);
  return (e - 1.f) * frcp_(e + 1.f);
}

__device__ __forceinline__ void gload16(const void* g, void* l) {
  __builtin_amdgcn_global_load_lds(
      (const __attribute__((address_space(1))) void*)g,
      (__attribute__((address_space(3))) void*)l, 16, 0, 0);
}

// merged prep: blocks 0..2047 transpose/interleave W; blocks 2048.. cast emb
__global__ __launch_bounds__(256)
void prep_all(const float* __restrict__ Wiou, const float* __restrict__ Wf,
              const float* __restrict__ biou, const float* __restrict__ bfv,
              const float* __restrict__ emb,
              f16* __restrict__ Btp, float* __restrict__ bcomb,
              f16* __restrict__ embh)
{
  int b = blockIdx.x;
  if (b < 2048) {
    int c = b;                   // interleaved col: c = 4*n + gate
    int n = c >> 2, g = c & 3;
    for (int k = threadIdx.x; k < 768; k += 256) {
      float v = (g < 3) ? Wiou[(size_t)k*1536 + g*512 + n] : Wf[(size_t)k*512 + n];
      Btp[(size_t)c*768 + k] = (f16)v;
    }
    if (threadIdx.x == 0) bcomb[c] = (g < 3) ? biou[g*512 + n] : bfv[n];
  } else {
    size_t i = (size_t)(b - 2048)*256 + threadIdx.x;   // 2000*256 total
    embh[i] = (f16)emb[i];
  }
}

// mode: 0 = inner pair level, 1 = leaf (K=256, csum=0), 2 = root (64 rows -> d_out)
// Block: 256 thr = 4 waves (2 wm x 2 wn). Tile: 128 wcols x 128 rows, BK=32.
// Grid: (pairs, 16) -- pair fast dim => same-pair col-blocks share an XCD L2.
// LDS buffers: buf b at smem + b*16384; W tile [128 rows][64B] at +0, C tile
// at +8192. Row r's 16B slot s holds global k-slot s ^ ((r>>1)&3) (XOR
// involution on the pre-swizzled global source, applied again on ds_read).
template<bool DEEP>
__global__ __launch_bounds__(256)
void lstm_level(const int* __restrict__ ast,
                const f16* __restrict__ embh,
                const f16* __restrict__ Btp,
                const float* __restrict__ bcomb,
                const f16* __restrict__ hsum_in,
                const float* __restrict__ csum_in,
                f16* __restrict__ hsum_out,
                float* __restrict__ csum_out,
                float* __restrict__ out_root,
                int level_start, int k_total, int mode)
{
  __shared__ __align__(16) char smem[DEEP ? 65536 : 36864];
  __shared__ int s_tok[128];
  float* csLDS = (float*)smem;              // epilogue: [128][EST]
  float* hLDS  = (float*)(smem + 18432);    // epilogue: [64][EST]
  float* cLDS  = (float*)(smem + 27648);    // epilogue: [64][EST]

  const int t = threadIdx.x;
  const int pair = blockIdx.x;
  const int bm = blockIdx.y;            // n-block (32 n per block)
  const int R0 = pair * 128;
  const int w = t >> 6, wm = w >> 1, wn = w & 1;
  const int lane = t & 63, l15 = lane & 15, kg4 = lane >> 4;
  const int n0 = bm * 32;
  const bool leaf = (mode == 1);

  if (t < 128) {
    int node = (mode == 2) ? 0 : (pair*2 + (t >> 6));
    s_tok[t] = ast[(size_t)(t & 63)*Nn + level_start + node];
  }

  // coalesced csum prefetch for the epilogue (in flight across the K-loop)
  float4 cs_pre[4];
  if (!leaf) {
    int row = t >> 1;
    int rows_cs = (mode == 2) ? 64 : 128;
    if (row < rows_cs) {
      const float* src = csum_in + (size_t)(R0 + row)*Hn + n0 + (t & 1)*16;
#pragma unroll
      for (int j = 0; j < 4; ++j) cs_pre[j] = *(const float4*)(src + j*4);
    } else {
#pragma unroll
      for (int j = 0; j < 4; ++j) cs_pre[j] = make_float4(0.f,0.f,0.f,0.f);
    }
  }
  __syncthreads();   // s_tok visible

  // ---- per-thread staging state (loop-invariant) ----
  const int srow = lane >> 2, sslot = lane & 3;
  const int rb0 = w*32, rb1 = w*32 + 16;
  const int row0 = rb0 + srow, row1 = rb1 + srow;
  const int ss0 = sslot ^ ((row0 >> 1) & 3), ss1 = sslot ^ ((row1 >> 1) & 3);
  const size_t wo0 = (size_t)(bm*128 + row0)*768 + ss0*8;
  const size_t wo1 = (size_t)(bm*128 + row1)*768 + ss1*8;
  const size_t ce0 = (size_t)s_tok[row0]*En + ss0*8;
  const size_t ce1 = (size_t)s_tok[row1]*En + ss1*8;
  const int rg0 = (mode == 2) ? (row0 & 63) : (R0 + row0);
  const int rg1 = (mode == 2) ? (row1 & 63) : (R0 + row1);
  const ptrdiff_t ch0 = (ptrdiff_t)rg0*Hn + ss0*8 - En;
  const ptrdiff_t ch1 = (ptrdiff_t)rg1*Hn + ss1*8 - En;
  const int klim0 = En - ss0*8, klim1 = En - ss1*8;

#define STAGE(bufc, K0)                                                        \
  {                                                                            \
    gload16(Btp + wo0 + (K0), (bufc) + rb0*64);                                \
    gload16(((K0) < klim0 ? embh + ce0 + (K0) : hsum_in + ch0 + (K0)),         \
            (bufc) + 8192 + rb0*64);                                           \
    gload16(Btp + wo1 + (K0), (bufc) + rb1*64);                                \
    gload16(((K0) < klim1 ? embh + ce1 + (K0) : hsum_in + ch1 + (K0)),         \
            (bufc) + 8192 + rb1*64);                                           \
  }

  // ---- loop-invariant ds_read byte offsets ----
  int offW[4], offC[4];
#pragma unroll
  for (int mi = 0; mi < 4; ++mi) {
    int row = wm*64 + mi*16 + l15;
    offW[mi] = row*64 + (kg4 ^ ((row >> 1) & 3))*16;
  }
#pragma unroll
  for (int ni = 0; ni < 4; ++ni) {
    int row = (ni >> 1)*64 + wn*32 + (ni & 1)*16 + l15;
    offC[ni] = 8192 + row*64 + (kg4 ^ ((row >> 1) & 3))*16;
  }

  f32x4 acc[4][4];
#pragma unroll
  for (int i = 0; i < 4; ++i)
#pragma unroll
    for (int j = 0; j < 4; ++j) acc[i][j] = (f32x4){0.f,0.f,0.f,0.f};

  const int nsteps = k_total >> 5;   // 8 (leaf) or 24 -- always % 4 == 0

  if constexpr (DEEP) {
    // ---- 4-buffer ring, counted vmcnt, stage-ahead 2 (latency-bound grids) ----
    STAGE(smem, 0);
    __builtin_amdgcn_sched_barrier(0);
    STAGE(smem + 16384, 32);
    __builtin_amdgcn_sched_barrier(0);

    for (int s = 0; s < nsteps; ++s) {
      if (s + 2 < nsteps) {
        char* nb = smem + ((s + 2) & 3)*16384;
        STAGE(nb, (s + 2) << 5);
        __builtin_amdgcn_sched_barrier(0);
        asm volatile("s_waitcnt vmcnt(8)" ::: "memory");   // buf s done; s+1,s+2 in flight
      } else if (s + 2 == nsteps) {
        asm volatile("s_waitcnt vmcnt(4)" ::: "memory");
      } else {
        asm volatile("s_waitcnt vmcnt(0)" ::: "memory");
      }
      __builtin_amdgcn_s_barrier();
      __builtin_amdgcn_sched_barrier(0);

      const char* cur = smem + (s & 3)*16384;
      f16x8 aW[4], aC[4];
#pragma unroll
      for (int mi = 0; mi < 4; ++mi) aW[mi] = *(const f16x8*)(cur + offW[mi]);
#pragma unroll
      for (int ni = 0; ni < 4; ++ni) aC[ni] = *(const f16x8*)(cur + offC[ni]);
#pragma unroll
      for (int mi = 0; mi < 4; ++mi)
#pragma unroll
        for (int ni = 0; ni < 4; ++ni)
          acc[mi][ni] = __builtin_amdgcn_mfma_f32_16x16x32_f16(aW[mi], aC[ni], acc[mi][ni], 0, 0, 0);
    }
    // last compute buffer is buf3 (48-64K); epilogue alias (0-36.9K) is free,
    // and the final pre-compute barrier ordered all older buffer reads.
    __builtin_amdgcn_s_barrier();   // all waves done reading before phase A
  } else {
    // ---- 2-buffer, barrier-per-step (TLP-rich grids: 4 blocks/CU) ----
    char* cur = smem;
    char* nxt = smem + 16384;
    STAGE(cur, 0);
    __syncthreads();
    for (int s = 0; s < nsteps; ++s) {
      if (s + 1 < nsteps) STAGE(nxt, (s + 1) << 5);

      f16x8 aW[4], aC[4];
#pragma unroll
      for (int mi = 0; mi < 4; ++mi) aW[mi] = *(const f16x8*)(cur + offW[mi]);
#pragma unroll
      for (int ni = 0; ni < 4; ++ni) aC[ni] = *(const f16x8*)(cur + offC[ni]);
#pragma unroll
      for (int mi = 0; mi < 4; ++mi)
#pragma unroll
        for (int ni = 0; ni < 4; ++ni)
          acc[mi][ni] = __builtin_amdgcn_mfma_f32_16x16x32_f16(aW[mi], aC[ni], acc[mi][ni], 0, 0, 0);

      __syncthreads();   // drains STAGE (vmcnt0) + releases cur
      char* tmp = cur; cur = nxt; nxt = tmp;
    }
  }

  // ================= epilogue =================
  // phase A: csum regs -> LDS (lane-local layout)
  if (!leaf) {
    int row = t >> 1;
    int rows_cs = (mode == 2) ? 64 : 128;
    if (row < rows_cs) {
      float* dst = csLDS + row*EST + (t & 1)*16;
#pragma unroll
      for (int j = 0; j < 4; ++j) *(float4*)(dst + j*4) = cs_pre[j];
    }
  }
  __syncthreads();

  float hres[4][2], cres[4][2];
#pragma unroll
  for (int mi = 0; mi < 4; ++mi) {
    int nl = wm*16 + mi*4 + kg4;
    float4 bc = *(const float4*)(bcomb + (size_t)(n0 + nl)*4);
#pragma unroll
    for (int pi = 0; pi < 2; ++pi) {
      int brow = wn*32 + pi*16 + l15;
      f32x4 a0 = acc[mi][pi];                // sibling 0
      float i0 = sigm(a0[0] + bc.x);
      float o0 = sigm(a0[1] + bc.y);
      float u0 = ftanh(a0[2] + bc.z);
      float f0 = sigm(a0[3] + bc.w);
      float cs0 = leaf ? 0.f : csLDS[brow*EST + nl];
      float c0 = i0*u0 + f0*cs0;
      float h0 = o0 * ftanh(c0);
      if (mode == 2) {
        hres[mi][pi] = h0; cres[mi][pi] = 0.f;
      } else {
        f32x4 a1 = acc[mi][2 + pi];          // sibling 1
        float i1 = sigm(a1[0] + bc.x);
        float o1 = sigm(a1[1] + bc.y);
        float u1 = ftanh(a1[2] + bc.z);
        float f1 = sigm(a1[3] + bc.w);
        float cs1 = leaf ? 0.f : csLDS[(64 + brow)*EST + nl];
        float c1 = i1*u1 + f1*cs1;
        float h1 = o1 * ftanh(c1);
        hres[mi][pi] = h0 + h1;
        cres[mi][pi] = c0 + c1;
      }
    }
  }
  __syncthreads();

  // phase B: results -> LDS in (brow, nl)
#pragma unroll
  for (int mi = 0; mi < 4; ++mi) {
    int nl = wm*16 + mi*4 + kg4;
#pragma unroll
    for (int pi = 0; pi < 2; ++pi) {
      int brow = wn*32 + pi*16 + l15;
      hLDS[brow*EST + nl] = hres[mi][pi];
      if (mode != 2) cLDS[brow*EST + nl] = cres[mi][pi];
    }
  }
  __syncthreads();

  // coalesced stores: thread t -> row r = t>>2, cols c0 = (t&3)*8
  {
    int r = t >> 2;
    int c0 = (t & 3) * 8;
    if (mode == 2) {
      float4 v0 = *(const float4*)(hLDS + r*EST + c0);
      float4 v1 = *(const float4*)(hLDS + r*EST + c0 + 4);
      float* dst = out_root + (size_t)r*Hn + n0 + c0;
      *(float4*)dst = v0;
      *(float4*)(dst + 4) = v1;
    } else {
      f16x8 hv;
#pragma unroll
      for (int i = 0; i < 8; ++i) hv[i] = (f16)hLDS[r*EST + c0 + i];
      size_t orow = (size_t)(pair*64 + r)*Hn + n0 + c0;
      *(f16x8*)(hsum_out + orow) = hv;
      float4 v0 = *(const float4*)(cLDS + r*EST + c0);
      float4 v1 = *(const float4*)(cLDS + r*EST + c0 + 4);
      *(float4*)(csum_out + orow) = v0;
      *(float4*)(csum_out + orow + 4) = v1;
    }
  }
}

extern "C" void kernel_launch(void* const* d_in, const int* in_sizes, int n_in,
                              void* d_out, int out_size, void* d_ws, size_t ws_size,
                              hipStream_t stream) {
  const int*   ast  = (const int*)d_in[0];
  // d_in[1] = parent (int64): unused, tree is the fixed heap (i-1)/2
  const float* emb  = (const float*)d_in[2];
  const float* Wiou = (const float*)d_in[3];
  const float* biou = (const float*)d_in[4];
  const float* Wf   = (const float*)d_in[5];
  const float* bfv  = (const float*)d_in[6];
  float* out = (float*)d_out;

  char* ws = (char*)d_ws;
  f16*   Btp   = (f16*)ws;    ws += (size_t)2048*768*2;
  float* bcomb = (float*)ws;  ws += (size_t)2048*4;
  f16*   embh  = (f16*)ws;    ws += (size_t)2000*256*2;
  f16*   hA    = (f16*)ws;    ws += (size_t)16384*512*2;
  float* cA    = (float*)ws;  ws += (size_t)16384*512*4;
  f16*   hB    = (f16*)ws;    ws += (size_t)8192*512*2;
  float* cB    = (float*)ws;  ws += (size_t)8192*512*4;

  prep_all<<<4048, 256, 0, stream>>>(Wiou, Wf, biou, bfv, emb, Btp, bcomb, embh);

  // leaf level l=9 (512 nodes, K=256) -> level-8 sums into set A
  lstm_level<false><<<dim3(256, 16), 256, 0, stream>>>(
      ast, embh, Btp, bcomb, nullptr, nullptr, hA, cA, nullptr, 511, En, 1);

  const f16* ih = hA; const float* ic = cA; int wsel = 1;
  for (int l = 8; l >= 1; --l) {
    f16*   oh = wsel ? hB : hA;
    float* oc = wsel ? cB : cA;
    if (l >= 7) {
      lstm_level<false><<<dim3(1 << (l - 1), 16), 256, 0, stream>>>(
          ast, embh, Btp, bcomb, ih, ic, oh, oc, nullptr, (1 << l) - 1, En + Hn, 0);
    } else {
      lstm_level<true><<<dim3(1 << (l - 1), 16), 256, 0, stream>>>(
          ast, embh, Btp, bcomb, ih, ic, oh, oc, nullptr, (1 << l) - 1, En + Hn, 0);
    }
    ih = oh; ic = oc; wsel ^= 1;
  }
  // root (64 rows): reads level-0 sums, writes h_root fp32 to d_out
  lstm_level<true><<<dim3(1, 16), 256, 0, stream>>>(
      ast, embh, Btp, bcomb, ih, ic, nullptr, nullptr, out, 0, En + Hn, 2);
}